// Round 10
// baseline (198.572 us; speedup 1.0000x reference)
//
#include <hip/hip_runtime.h>

// ---------------------------------------------------------------------------
// MultiHeadAttention: B=2, S=2048, H=16, Dh=64, D=1024, causal mask, fp32 I/O.
// R20: attention = PAIRED-TILE block with shared staging + dbuf.
//      Block (bh,t), 512 thr: waves 0-3 = q-tile jA=t, waves 4-7 = jB=15-t,
//      each wave 32 q-rows (R14/R19-verified compute).  ONE K/V stage per
//      kv-pair feeds both tiles (group g active iff pair<=j_g, diag at ==).
//      Work/block uniform (17 group-pair units); NO merge (disjoint q-rows);
//      R17 dbuf schedule (prefetch K-DMA + V-regs before compute, 1 barrier/
//      pair).  Grid 256 (1/CU); 8 blocks per bh on one XCD.  LDS 64KB.
//      launch_bounds(512,1): ~112 VGPR must not be capped (R15 spill lesson).
//      GEMMs unchanged (R14 conflict-free swizzled staging, verified).
// ---------------------------------------------------------------------------

#define B_   2
#define S_   2048
#define H_   16
#define DH_  64
#define D_   1024
#define M_   (B_ * S_)          // 4096 rows

typedef __attribute__((ext_vector_type(8))) short short8;
typedef __attribute__((ext_vector_type(4))) short short4_t;
typedef float v4f __attribute__((ext_vector_type(4)));

__device__ __forceinline__ short f2bf(float f) {
    union { float f; unsigned u; } v; v.f = f;
    unsigned r = v.u + 0x7fffu + ((v.u >> 16) & 1u);  // round-to-nearest-even
    return (short)(r >> 16);
}

#if __has_builtin(__builtin_amdgcn_exp2f)
#define EXP2(x) __builtin_amdgcn_exp2f(x)
#else
#define EXP2(x) exp2f(x)
#endif

// pack two f32 -> dword of two truncated bf16 (low short = a, high = b)
__device__ __forceinline__ unsigned pack2(float a, float b) {
    return (__float_as_uint(a) >> 16) | (__float_as_uint(b) & 0xFFFF0000u);
}

// async 16B/lane global -> LDS DMA (lane l deposits at lds + l*16)
__device__ __forceinline__ void gl2lds16(const short* g, short* l) {
    __builtin_amdgcn_global_load_lds(
        (const __attribute__((address_space(1))) unsigned int*)g,
        (__attribute__((address_space(3))) unsigned int*)l,
        16, 0, 0);
}

// ---------------------------------------------------------------------------
// Kernel 1: cast X and Wq,Wk,Wv,Wo fp32 -> bf16.  8 elems/thread, 16B stores.
// ---------------------------------------------------------------------------
__global__ __launch_bounds__(256) void cast_kernel(
    const float* __restrict__ X,
    const float* __restrict__ Wq, const float* __restrict__ Wk,
    const float* __restrict__ Wv, const float* __restrict__ Wo,
    short* __restrict__ Xb, short* __restrict__ Wb)
{
    const int NX8 = (M_ * D_) / 8;      // 524,288
    const int NW8 = (D_ * D_) / 8;      // 131,072
    int idx = blockIdx.x * 256 + threadIdx.x;   // 1,048,576 threads

    const float* src; short* dst; int off;
    if (idx < NX8) { src = X; dst = Xb; off = idx; }
    else {
        int r = idx - NX8;
        int sel = r >> 17;
        int o = r & (NW8 - 1);
        src = (sel == 0) ? Wq : (sel == 1) ? Wk : (sel == 2) ? Wv : Wo;
        dst = Wb + sel * (D_ * D_);
        off = o;
    }
    float4 f0 = ((const float4*)src)[off * 2];
    float4 f1 = ((const float4*)src)[off * 2 + 1];
    short8 s;
    s[0] = f2bf(f0.x); s[1] = f2bf(f0.y); s[2] = f2bf(f0.z); s[3] = f2bf(f0.w);
    s[4] = f2bf(f1.x); s[5] = f2bf(f1.y); s[6] = f2bf(f1.z); s[7] = f2bf(f1.w);
    *(short8*)(dst + (size_t)off * 8) = s;
}

// ---------------------------------------------------------------------------
// Kernel 2: C = A(bf16,[M,K]) @ W(bf16,[N,K])^T + bias.  BM=128, BK=64.
// m97 staging into XOR-16B-chunk-SWIZZLED LDS tiles: gl2lds dest linear,
// global source chunk = (lane&7)^rsub; fragment read chunk = (kk*4+lg)^(lm&7)
// MODE 0 (BN=128): fused QKV, N=3072.  Q,K natural [bh][s][64]; V -> Vt
//                  [bh][64][s] via transposed LDS epilogue, 16B/lane stores.
//                  Q is PRE-SCALED by 0.125*log2(e) (attn exp2-domain fold).
// MODE 2 (BN=64):  fp32 out [M,1024] (final projection), 512 blocks (2/CU).
// XCD-aware flat-grid swizzle: xcd=bid&7 owns 4 m-rows.
// ---------------------------------------------------------------------------
template<int BN, int MODE>
__global__ __launch_bounds__(256) void gemm_kernel(
    const short* __restrict__ A, const short* __restrict__ W,
    const float* __restrict__ bq, const float* __restrict__ bk,
    const float* __restrict__ bv, void* __restrict__ out,
    int M, int N, int K)
{
    constexpr int SM = (MODE == 0) ? 18432 : (8192 + BN * 64);
    __shared__ __align__(16) short smem[SM];
    short* As = smem;                                  // [128][64] swizzled
    short* Bs = smem + 8192;                           // [BN][64]  swizzled

    const int t    = threadIdx.x;
    const int lane = t & 63;
    const int wave = t >> 6;

    const int bid = blockIdx.x;
    const int by  = ((bid & 7) << 2) + ((bid >> 3) & 3);
    const int bx  = bid >> 5;
    const int m0 = by * 128;
    const int n0 = bx * BN;

    const int wm = (wave >> 1) * 64;
    const int wn = (wave & 1) * (BN / 2);
    constexpr int NJ  = BN / 32;       // acc cols per wave (4 or 2)
    constexpr int BIT = BN / 32;       // B staging insts per wave

    v4f acc[4][NJ] = {};

    // staging: inst i2 covers 8 rows; lane l -> row +(l>>3),
    // SOURCE chunk ((l&7)^(l>>3))*8 shorts  (inverse of the read swizzle)
    const int rsub = lane >> 3;
    const int csw  = ((lane & 7) ^ rsub) * 8;
    const short* Ag = A + (size_t)(m0 + wave * 32 + rsub) * K + csw;
    const short* Wg = W + (size_t)(n0 + wave * (BN / 4) + rsub) * K + csw;
    short* Asw = As + (wave * 32) * 64;
    short* Bsw = Bs + (wave * (BN / 4)) * 64;

    const int lm = lane & 15;
    const int lg = lane >> 4;
    const int lm7 = lm & 7;

    for (int k0 = 0; k0 < K; k0 += 64) {
        #pragma unroll
        for (int i2 = 0; i2 < 4; ++i2)
            gl2lds16(Ag + (size_t)(i2 * 8) * K + k0, Asw + i2 * 512);
        #pragma unroll
        for (int i2 = 0; i2 < BIT; ++i2)
            gl2lds16(Wg + (size_t)(i2 * 8) * K + k0, Bsw + i2 * 512);
        __syncthreads();   // drains vmcnt(0): tiles visible

        #pragma unroll
        for (int kk = 0; kk < 2; ++kk) {
            const int ch = (kk * 4 + lg) ^ lm7;      // swizzled 16B chunk
            short8 af[4], bf[NJ];
            #pragma unroll
            for (int i = 0; i < 4; ++i)
                af[i] = *(const short8*)((const char*)As + (wm + i * 16 + lm) * 128 + ch * 16);
            #pragma unroll
            for (int j = 0; j < NJ; ++j)
                bf[j] = *(const short8*)((const char*)Bs + (wn + j * 16 + lm) * 128 + ch * 16);
            #pragma unroll
            for (int i = 0; i < 4; ++i)
                #pragma unroll
                for (int j = 0; j < NJ; ++j)
                    acc[i][j] = __builtin_amdgcn_mfma_f32_16x16x32_bf16(af[i], bf[j], acc[i][j], 0, 0, 0);
        }
        __syncthreads();   // all reads done before next overwrite
    }

    const int sel = n0 >> 10;          // 0=Q 1=K 2=V (block-uniform, MODE 0)
    const float* bias = (MODE == 2) ? bq : (sel == 0) ? bq : (sel == 1) ? bk : bv;

    if constexpr (MODE == 2) {
        const int colb = n0 + wn + lm;
        const int rowb = m0 + wm + lg * 4;
        #pragma unroll
        for (int j = 0; j < NJ; ++j) {
            int col = colb + j * 16;
            float bv_ = bias[col];
            #pragma unroll
            for (int i = 0; i < 4; ++i)
                #pragma unroll
                for (int r = 0; r < 4; ++r)
                    ((float*)out)[(size_t)(rowb + i * 16 + r) * 1024 + col] = acc[i][j][r] + bv_;
        }
    } else {
        // bf16 via wave-private LDS region (72-padded); 16B/lane wide stores.
        short* Es = smem + wave * (64 * 72);
        const int cb = (n0 + wn) & 1023;
        #pragma unroll
        for (int j = 0; j < 4; ++j) {
            float bv_ = bias[cb + j * 16 + lm];
            #pragma unroll
            for (int i = 0; i < 4; ++i)
                #pragma unroll
                for (int r = 0; r < 4; ++r) {
                    float vv = acc[i][j][r] + bv_;
                    if (sel == 0) vv *= 0.1803368867f;   // 0.125*log2(e): exp2-domain Q
                    if (sel < 2)    // Es[s_local][d]
                        Es[(i * 16 + lg * 4 + r) * 72 + j * 16 + lm] = f2bf(vv);
                    else            // V: Es[d][s_local]  (transposed)
                        Es[(j * 16 + lm) * 72 + i * 16 + lg * 4 + r] = f2bf(vv);
                }
        }
        __asm__ __volatile__("s_waitcnt lgkmcnt(0)" ::: "memory");
        short* outQKV = (short*)out;           // [Qh | Kb | Vt]
        const int rl = lane >> 3;
        const int c8 = (lane & 7) * 8;
        const int h  = cb >> 6;
        const int b  = (m0 + wm) >> 11;
        const int bh = (b << 4) + h;
        if (sel < 2) {
            #pragma unroll
            for (int it = 0; it < 8; ++it) {
                int row_l = it * 8 + rl;
                short8 vrow = *(const short8*)&Es[row_l * 72 + c8];
                int s = (m0 + wm + row_l) & 2047;
                *(short8*)(outQKV + (size_t)sel * 4194304 +
                           ((size_t)bh * S_ + s) * DH_ + c8) = vrow;
            }
        } else {
            const int s0 = (m0 + wm) & 2047;
            #pragma unroll
            for (int it = 0; it < 8; ++it) {
                int d_l = it * 8 + rl;
                short8 vrow = *(const short8*)&Es[d_l * 72 + c8];
                *(short8*)(outQKV + (size_t)2 * 4194304 +
                           ((size_t)bh << 17) + ((size_t)d_l << 11) + s0 + c8) = vrow;
            }
        }
    }
}

// ---------------------------------------------------------------------------
// Kernel 3: causal flash attention, PAIRED-TILE blocks, shared staging, dbuf.
// Block (bh, t): waves 0-3 (group 0) = q-tile jA=t, waves 4-7 (group 1) =
// q-tile jB=15-t; wave wg owns q-rows jg*128 + wg*32 (R14/R19 32-q compute).
// kv pairs i = 0..jB; group g computes pair i iff i <= j_g (diag at i==j_g).
// ONE staging per pair (all 8 waves stage: K 2 DMA/wave, V 2 loads + writes
// R17 split) serves both groups.  Dbuf: prefetch pair i+1 (K-DMA -> idle
// buffer, V -> 8 VGPR) before compute(i); writeV after; ONE barrier/pair.
// No merge: groups own disjoint q-rows; every wave stores its own epilogue.
// Uniform 17 group-pair units/block.  Grid 256 = (xcd, bh, t): 1 block/CU,
// 8 blocks per bh on one XCD (K/V 512KB << 4MB L2).  LDS 2x32KB = 64KB.
// ---------------------------------------------------------------------------
__global__ __launch_bounds__(512, 1) void attn_kernel(
    const short* __restrict__ Q, const short* __restrict__ Kh,
    const short* __restrict__ Vt, short* __restrict__ ctx)
{
    __shared__ __align__(16) short sm[32768];   // 64KB: 2 x (Kt 8192 | Vp 8192)

    const int t    = threadIdx.x;
    const int lane = t & 63;
    const int w    = t >> 6;                     // 0..7
    const int wg   = w & 3;                      // wave within group
    const int g    = w >> 2;                     // 0 = tile jA, 1 = tile jB
    const int bid  = blockIdx.x;                 // 256 blocks

    const int xcd = bid & 7;
    const int bh  = (xcd << 2) + ((bid >> 3) & 3);
    const int tp  = bid >> 5;                    // 0..7
    const int jA  = tp;
    const int jB  = 15 - tp;
    const int jg  = g ? jB : jA;                 // this group's q-tile
    const int NT  = jB + 1;                      // staged kv pairs (9..16)
    const int qr0 = jg * 128 + wg * 32;          // this wave's 32 q-rows

    const int lm = lane & 15;
    const int lg = lane >> 4;

    const short* Qb = Q  + (size_t)bh * S_ * DH_;
    const short* Kb = Kh + (size_t)bh * S_ * DH_;
    const short* Vb = Vt + ((size_t)bh << 17);

    // ---- staging helpers (R17 8-wave split, verified layouts) ----
    const int rsubK = lane >> 3;                         // 0..7
    const int cswK  = ((lane & 7) ^ rsubK) * 8;          // swizzled src chunk
    const int dV    = w * 8 + (lane >> 3);               // V^T row this thread owns
    const int s3V   = dV & 7;

    auto stageK = [&](int kv0, short* Kt) {
        #pragma unroll
        for (int i2 = 0; i2 < 2; ++i2) {
            const int rb = w * 16 + i2 * 8;
            gl2lds16(Kb + (size_t)(kv0 + rb + rsubK) * 64 + cswK, Kt + rb * 64);
        }
    };
    auto loadV = [&](int kv0, short8* vld) {
        #pragma unroll
        for (int m = 0; m < 2; ++m) {
            const int cm = (lane & 7) + 8 * m;           // 16B piece index
            vld[m] = *(const short8*)(Vb + (size_t)dV * 2048 + kv0 + cm * 8);
        }
    };
    auto writeV = [&](const short8* vld, short* Vp) {
        char* vrow = (char*)Vp + dV * 256;
        #pragma unroll
        for (int m = 0; m < 2; ++m) {
            const int cm = (lane & 7) + 8 * m;
            const int u  = cm >> 3, kk = (cm >> 2) & 1;
            const int q0off = ((cm & 1) << 4) + ((cm >> 1) & 1) * 4;  // shorts
            const int bA = (u * 64 + kk * 32 + q0off) * 2;            // bytes
            const int pA = ((((bA >> 4) ^ s3V) << 4) | (bA & 15));
            const int bB = bA + 16;
            const int pB = ((((bB >> 4) ^ s3V) << 4) | (bB & 15));
            *(short4_t*)(vrow + pA) = __builtin_shufflevector(vld[m], vld[m], 0, 1, 2, 3);
            *(short4_t*)(vrow + pB) = __builtin_shufflevector(vld[m], vld[m], 4, 5, 6, 7);
        }
    };

    // Q as B-operand (pre-scaled by 0.125*log2e at the QKV GEMM):
    short8 qf[2][2];
    #pragma unroll
    for (int t2 = 0; t2 < 2; ++t2)
        #pragma unroll
        for (int kk = 0; kk < 2; ++kk)
            qf[t2][kk] = *(const short8*)(Qb + (size_t)(qr0 + t2 * 16 + lm) * DH_ + kk * 32 + lg * 8);

    float m_i[2] = {-1e30f, -1e30f}, l_i[2] = {0.f, 0.f};
    v4f o[2][4] = {};   // O^T[d = i*16+lg*4+r][q = t2*16+lm]

    // ---- prologue: stage pair 0 into buf0 ----
    short8 vpre[2];
    stageK(0, sm);
    loadV(0, vpre);
    writeV(vpre, sm + 8192);
    __syncthreads();            // drains K DMA (vmcnt) + V writes (lgkm)

    int cur = 0;
    for (int it = 0; it < NT; ++it) {
        const int kv0 = it * 128;
        const bool act   = (it <= jg);           // group computes this pair?
        const bool dpair = (it == jg);           // group's diagonal pair
        const bool pre   = (it + 1 < NT);
        short* Kt = sm + cur * 16384;
        short* Vp = Kt + 8192;

        // ---- prefetch next pair: K DMA into other buf, V into regs ----
        if (pre) {
            short* Ktn = sm + (cur ^ 1) * 16384;
            stageK(kv0 + 128, Ktn);
            loadV(kv0 + 128, vpre);
        }

        if (act) {
            // ---- V^T A-frags from Vp: one swizzled 16B read each ----
            short8 vf[2][2][4];
            #pragma unroll
            for (int u = 0; u < 2; ++u)
                #pragma unroll
                for (int kk = 0; kk < 2; ++kk)
                    #pragma unroll
                    for (int i = 0; i < 4; ++i) {
                        const int d = i * 16 + lm;
                        const int ch = (u * 8 + kk * 4 + lg) ^ (lm & 7);
                        vf[u][kk][i] = *(const short8*)((const char*)Vp + d * 256 + ch * 16);
                    }

            // ---- S^T = K Q^T, both subtiles (32 MFMAs) ----
            v4f sc[2][2][4] = {};   // [t2][u][jj]
            #pragma unroll
            for (int u = 0; u < 2; ++u) {
                short8 kf[2][4];
                #pragma unroll
                for (int kk = 0; kk < 2; ++kk)
                    #pragma unroll
                    for (int jj = 0; jj < 4; ++jj) {
                        const int row = u * 64 + jj * 16 + lm;
                        const int ch  = (kk * 4 + lg) ^ (lm & 7);
                        kf[kk][jj] = *(const short8*)((const char*)Kt + row * 128 + ch * 16);
                    }
                #pragma unroll
                for (int kk = 0; kk < 2; ++kk)
                    #pragma unroll
                    for (int t2 = 0; t2 < 2; ++t2)
                        #pragma unroll
                        for (int jj = 0; jj < 4; ++jj)
                            sc[t2][u][jj] = __builtin_amdgcn_mfma_f32_16x16x32_bf16(kf[kk][jj], qf[t2][kk], sc[t2][u][jj], 0, 0, 0);
            }

            // one online-softmax step per t2 over 128 kv
            float alpha[2];
            short8 pf[2][2][2];     // [t2][u][kk]
            #pragma unroll
            for (int t2 = 0; t2 < 2; ++t2) {
                float x[2][4][4];
                const int q = qr0 + t2 * 16 + lm;
                #pragma unroll
                for (int u = 0; u < 2; ++u)
                    #pragma unroll
                    for (int jj = 0; jj < 4; ++jj)
                        #pragma unroll
                        for (int r = 0; r < 4; ++r) {
                            float v = sc[t2][u][jj][r];
                            if (dpair && (kv0 + u * 64 + jj * 16 + lg * 4 + r > q)) v = -1e30f;
                            x[u][jj][r] = v;
                        }
                float m8[8];
                #pragma unroll
                for (int z = 0; z < 8; ++z) {
                    const float* xz = x[z >> 2][z & 3];
                    m8[z] = fmaxf(fmaxf(xz[0], xz[1]), fmaxf(xz[2], xz[3]));
                }
                float rm = fmaxf(fmaxf(fmaxf(m8[0], m8[1]), fmaxf(m8[2], m8[3])),
                                 fmaxf(fmaxf(m8[4], m8[5]), fmaxf(m8[6], m8[7])));
                rm = fmaxf(rm, __shfl_xor(rm, 16, 64));
                rm = fmaxf(rm, __shfl_xor(rm, 32, 64));

                const float mn = fmaxf(m_i[t2], rm);
                alpha[t2] = EXP2(m_i[t2] - mn);
                m_i[t2] = mn;

                float s8[8];
                #pragma unroll
                for (int z = 0; z < 8; ++z) {
                    float* xz = x[z >> 2][z & 3];
                    xz[0] = EXP2(xz[0] - mn); xz[1] = EXP2(xz[1] - mn);
                    xz[2] = EXP2(xz[2] - mn); xz[3] = EXP2(xz[3] - mn);
                    s8[z] = (xz[0] + xz[1]) + (xz[2] + xz[3]);
                }
                float rs = ((s8[0] + s8[1]) + (s8[2] + s8[3])) + ((s8[4] + s8[5]) + (s8[6] + s8[7]));
                rs += __shfl_xor(rs, 16, 64);
                rs += __shfl_xor(rs, 32, 64);
                l_i[t2] = l_i[t2] * alpha[t2] + rs;

                #pragma unroll
                for (int u = 0; u < 2; ++u)
                    #pragma unroll
                    for (int kk = 0; kk < 2; ++kk) {
                        union { short8 s; uint4 d; } pk;
                        pk.d.x = pack2(x[u][2 * kk][0],     x[u][2 * kk][1]);
                        pk.d.y = pack2(x[u][2 * kk][2],     x[u][2 * kk][3]);
                        pk.d.z = pack2(x[u][2 * kk + 1][0], x[u][2 * kk + 1][1]);
                        pk.d.w = pack2(x[u][2 * kk + 1][2], x[u][2 * kk + 1][3]);
                        pf[t2][u][kk] = pk.s;
                    }
            }

            #pragma unroll
            for (int t2 = 0; t2 < 2; ++t2)
                #pragma unroll
                for (int i = 0; i < 4; ++i)
                    o[t2][i] *= alpha[t2];

            // O^T += V^T P^T  (32 MFMAs)
            #pragma unroll
            for (int u = 0; u < 2; ++u)
                #pragma unroll
                for (int kk = 0; kk < 2; ++kk)
                    #pragma unroll
                    for (int t2 = 0; t2 < 2; ++t2)
                        #pragma unroll
                        for (int i = 0; i < 4; ++i)
                            o[t2][i] = __builtin_amdgcn_mfma_f32_16x16x32_bf16(vf[u][kk][i], pf[t2][u][kk], o[t2][i], 0, 0, 0);
        }

        // ---- write prefetched V into the other buffer, then ONE barrier ----
        if (pre) writeV(vpre, sm + (cur ^ 1) * 16384 + 8192);
        __syncthreads();   // drains K-DMA (vmcnt) + V ds_writes (lgkm);
                           // all waves' reads of buf[cur] complete
        cur ^= 1;
    }

    // epilogue: every wave stores its own 32 q-rows (no merge needed)
    const int b = bh >> 4, hd = bh & 15;
    #pragma unroll
    for (int t2 = 0; t2 < 2; ++t2) {
        const float inv = 1.f / l_i[t2];
        const size_t base = ((size_t)(b * S_ + qr0 + t2 * 16 + lm) << 10) + (hd << 6) + lg * 4;
        #pragma unroll
        for (int i = 0; i < 4; ++i) {
            short4_t s4;
            #pragma unroll
            for (int r = 0; r < 4; ++r) s4[r] = f2bf(o[t2][i][r] * inv);
            *(short4_t*)(ctx + base + i * 16) = s4;
        }
    }
}

// ---------------------------------------------------------------------------
extern "C" void kernel_launch(void* const* d_in, const int* in_sizes, int n_in,
                              void* d_out, int out_size, void* d_ws, size_t ws_size,
                              hipStream_t stream) {
    const float* X  = (const float*)d_in[0];
    const float* Wq = (const float*)d_in[2];
    const float* bq = (const float*)d_in[3];
    const float* Wk = (const float*)d_in[4];
    const float* bk = (const float*)d_in[5];
    const float* Wv = (const float*)d_in[6];
    const float* bv = (const float*)d_in[7];
    const float* Wo = (const float*)d_in[8];
    const float* bo = (const float*)d_in[9];
    float* out = (float*)d_out;

    short* ws  = (short*)d_ws;
    short* Xb  = ws;                          // X bf16, 4,194,304
    short* Wb  = Xb + 4194304;                // [Wq|Wk|Wv|Wo] bf16
    short* Qh  = Wb + 4194304;                // [bh][s][64]  (pre-scaled)
    short* Kb  = Qh + 4194304;                // [bh][s][64]
    short* Vt  = Kb + 4194304;                // [bh][64][s] (written by gemm)
    short* Ctx = Vt + 4194304;                // [b*s][1024]

    cast_kernel<<<4096, 256, 0, stream>>>(X, Wq, Wk, Wv, Wo, Xb, Wb);

    // fused QKV projection: flat grid 24*32 = 768, swizzled in-kernel
    gemm_kernel<128, 0><<<768, 256, 0, stream>>>(
        Xb, Wb, bq, bk, bv, Qh, M_, 3 * D_, D_);

    // paired-tile shared-staging attention: 256 blocks x 512 threads (1/CU)
    attn_kernel<<<256, 512, 0, stream>>>(Qh, Kb, Vt, Ctx);

    // output projection: flat grid 16*32 = 512, swizzled in-kernel (2/CU)
    gemm_kernel<64, 2><<<512, 256, 0, stream>>>(
        Ctx, Wb + 3145728, bo, bo, bo, out, M_, D_, D_);
}

// Round 11
// 188.059 us; speedup vs baseline: 1.0559x; 1.0559x over previous
//
#include <hip/hip_runtime.h>

// ---------------------------------------------------------------------------
// MultiHeadAttention: B=2, S=2048, H=16, Dh=64, D=1024, causal mask, fp32 I/O.
// R21: attention = 32-q waves + wave-group kv-split (R19) + DOUBLE-BUFFERING
//      (R17), unlocked by 64-kv units: per group 2 bufs x (K 8KB + V 8KB)
//      = 32KB, x2 groups = 64KB exactly.  Per step each wave covers the same
//      64kv x 32q area as an R17 pair (32 MFMA) with HALF the LDS fragment
//      reads (16 b128 vs 32).  Both groups run exactly j+1 lockstep steps
//      (uniform, no idle waves — R20's flaw).  Compute block = R12-verified
//      64-kv tile; staging = R14/R17-verified layouts at width 64; merge =
//      R19-verified.  Mask via wave-uniform dmask (covers j=0 A-side diag).
//      GEMMs unchanged (R14 conflict-free swizzled staging, verified).
// ---------------------------------------------------------------------------

#define B_   2
#define S_   2048
#define H_   16
#define DH_  64
#define D_   1024
#define M_   (B_ * S_)          // 4096 rows

typedef __attribute__((ext_vector_type(8))) short short8;
typedef __attribute__((ext_vector_type(4))) short short4_t;
typedef float v4f __attribute__((ext_vector_type(4)));

__device__ __forceinline__ short f2bf(float f) {
    union { float f; unsigned u; } v; v.f = f;
    unsigned r = v.u + 0x7fffu + ((v.u >> 16) & 1u);  // round-to-nearest-even
    return (short)(r >> 16);
}

#if __has_builtin(__builtin_amdgcn_exp2f)
#define EXP2(x) __builtin_amdgcn_exp2f(x)
#else
#define EXP2(x) exp2f(x)
#endif

// pack two f32 -> dword of two truncated bf16 (low short = a, high = b)
__device__ __forceinline__ unsigned pack2(float a, float b) {
    return (__float_as_uint(a) >> 16) | (__float_as_uint(b) & 0xFFFF0000u);
}

// async 16B/lane global -> LDS DMA (lane l deposits at lds + l*16)
__device__ __forceinline__ void gl2lds16(const short* g, short* l) {
    __builtin_amdgcn_global_load_lds(
        (const __attribute__((address_space(1))) unsigned int*)g,
        (__attribute__((address_space(3))) unsigned int*)l,
        16, 0, 0);
}

// ---------------------------------------------------------------------------
// Kernel 1: cast X and Wq,Wk,Wv,Wo fp32 -> bf16.  8 elems/thread, 16B stores.
// ---------------------------------------------------------------------------
__global__ __launch_bounds__(256) void cast_kernel(
    const float* __restrict__ X,
    const float* __restrict__ Wq, const float* __restrict__ Wk,
    const float* __restrict__ Wv, const float* __restrict__ Wo,
    short* __restrict__ Xb, short* __restrict__ Wb)
{
    const int NX8 = (M_ * D_) / 8;      // 524,288
    const int NW8 = (D_ * D_) / 8;      // 131,072
    int idx = blockIdx.x * 256 + threadIdx.x;   // 1,048,576 threads

    const float* src; short* dst; int off;
    if (idx < NX8) { src = X; dst = Xb; off = idx; }
    else {
        int r = idx - NX8;
        int sel = r >> 17;
        int o = r & (NW8 - 1);
        src = (sel == 0) ? Wq : (sel == 1) ? Wk : (sel == 2) ? Wv : Wo;
        dst = Wb + sel * (D_ * D_);
        off = o;
    }
    float4 f0 = ((const float4*)src)[off * 2];
    float4 f1 = ((const float4*)src)[off * 2 + 1];
    short8 s;
    s[0] = f2bf(f0.x); s[1] = f2bf(f0.y); s[2] = f2bf(f0.z); s[3] = f2bf(f0.w);
    s[4] = f2bf(f1.x); s[5] = f2bf(f1.y); s[6] = f2bf(f1.z); s[7] = f2bf(f1.w);
    *(short8*)(dst + (size_t)off * 8) = s;
}

// ---------------------------------------------------------------------------
// Kernel 2: C = A(bf16,[M,K]) @ W(bf16,[N,K])^T + bias.  BM=128, BK=64.
// m97 staging into XOR-16B-chunk-SWIZZLED LDS tiles: gl2lds dest linear,
// global source chunk = (lane&7)^rsub; fragment read chunk = (kk*4+lg)^(lm&7)
// MODE 0 (BN=128): fused QKV, N=3072.  Q,K natural [bh][s][64]; V -> Vt
//                  [bh][64][s] via transposed LDS epilogue, 16B/lane stores.
//                  Q is PRE-SCALED by 0.125*log2(e) (attn exp2-domain fold).
// MODE 2 (BN=64):  fp32 out [M,1024] (final projection), 512 blocks (2/CU).
// XCD-aware flat-grid swizzle: xcd=bid&7 owns 4 m-rows.
// ---------------------------------------------------------------------------
template<int BN, int MODE>
__global__ __launch_bounds__(256) void gemm_kernel(
    const short* __restrict__ A, const short* __restrict__ W,
    const float* __restrict__ bq, const float* __restrict__ bk,
    const float* __restrict__ bv, void* __restrict__ out,
    int M, int N, int K)
{
    constexpr int SM = (MODE == 0) ? 18432 : (8192 + BN * 64);
    __shared__ __align__(16) short smem[SM];
    short* As = smem;                                  // [128][64] swizzled
    short* Bs = smem + 8192;                           // [BN][64]  swizzled

    const int t    = threadIdx.x;
    const int lane = t & 63;
    const int wave = t >> 6;

    const int bid = blockIdx.x;
    const int by  = ((bid & 7) << 2) + ((bid >> 3) & 3);
    const int bx  = bid >> 5;
    const int m0 = by * 128;
    const int n0 = bx * BN;

    const int wm = (wave >> 1) * 64;
    const int wn = (wave & 1) * (BN / 2);
    constexpr int NJ  = BN / 32;       // acc cols per wave (4 or 2)
    constexpr int BIT = BN / 32;       // B staging insts per wave

    v4f acc[4][NJ] = {};

    // staging: inst i2 covers 8 rows; lane l -> row +(l>>3),
    // SOURCE chunk ((l&7)^(l>>3))*8 shorts  (inverse of the read swizzle)
    const int rsub = lane >> 3;
    const int csw  = ((lane & 7) ^ rsub) * 8;
    const short* Ag = A + (size_t)(m0 + wave * 32 + rsub) * K + csw;
    const short* Wg = W + (size_t)(n0 + wave * (BN / 4) + rsub) * K + csw;
    short* Asw = As + (wave * 32) * 64;
    short* Bsw = Bs + (wave * (BN / 4)) * 64;

    const int lm = lane & 15;
    const int lg = lane >> 4;
    const int lm7 = lm & 7;

    for (int k0 = 0; k0 < K; k0 += 64) {
        #pragma unroll
        for (int i2 = 0; i2 < 4; ++i2)
            gl2lds16(Ag + (size_t)(i2 * 8) * K + k0, Asw + i2 * 512);
        #pragma unroll
        for (int i2 = 0; i2 < BIT; ++i2)
            gl2lds16(Wg + (size_t)(i2 * 8) * K + k0, Bsw + i2 * 512);
        __syncthreads();   // drains vmcnt(0): tiles visible

        #pragma unroll
        for (int kk = 0; kk < 2; ++kk) {
            const int ch = (kk * 4 + lg) ^ lm7;      // swizzled 16B chunk
            short8 af[4], bf[NJ];
            #pragma unroll
            for (int i = 0; i < 4; ++i)
                af[i] = *(const short8*)((const char*)As + (wm + i * 16 + lm) * 128 + ch * 16);
            #pragma unroll
            for (int j = 0; j < NJ; ++j)
                bf[j] = *(const short8*)((const char*)Bs + (wn + j * 16 + lm) * 128 + ch * 16);
            #pragma unroll
            for (int i = 0; i < 4; ++i)
                #pragma unroll
                for (int j = 0; j < NJ; ++j)
                    acc[i][j] = __builtin_amdgcn_mfma_f32_16x16x32_bf16(af[i], bf[j], acc[i][j], 0, 0, 0);
        }
        __syncthreads();   // all reads done before next overwrite
    }

    const int sel = n0 >> 10;          // 0=Q 1=K 2=V (block-uniform, MODE 0)
    const float* bias = (MODE == 2) ? bq : (sel == 0) ? bq : (sel == 1) ? bk : bv;

    if constexpr (MODE == 2) {
        const int colb = n0 + wn + lm;
        const int rowb = m0 + wm + lg * 4;
        #pragma unroll
        for (int j = 0; j < NJ; ++j) {
            int col = colb + j * 16;
            float bv_ = bias[col];
            #pragma unroll
            for (int i = 0; i < 4; ++i)
                #pragma unroll
                for (int r = 0; r < 4; ++r)
                    ((float*)out)[(size_t)(rowb + i * 16 + r) * 1024 + col] = acc[i][j][r] + bv_;
        }
    } else {
        // bf16 via wave-private LDS region (72-padded); 16B/lane wide stores.
        short* Es = smem + wave * (64 * 72);
        const int cb = (n0 + wn) & 1023;
        #pragma unroll
        for (int j = 0; j < 4; ++j) {
            float bv_ = bias[cb + j * 16 + lm];
            #pragma unroll
            for (int i = 0; i < 4; ++i)
                #pragma unroll
                for (int r = 0; r < 4; ++r) {
                    float vv = acc[i][j][r] + bv_;
                    if (sel == 0) vv *= 0.1803368867f;   // 0.125*log2(e): exp2-domain Q
                    if (sel < 2)    // Es[s_local][d]
                        Es[(i * 16 + lg * 4 + r) * 72 + j * 16 + lm] = f2bf(vv);
                    else            // V: Es[d][s_local]  (transposed)
                        Es[(j * 16 + lm) * 72 + i * 16 + lg * 4 + r] = f2bf(vv);
                }
        }
        __asm__ __volatile__("s_waitcnt lgkmcnt(0)" ::: "memory");
        short* outQKV = (short*)out;           // [Qh | Kb | Vt]
        const int rl = lane >> 3;
        const int c8 = (lane & 7) * 8;
        const int h  = cb >> 6;
        const int b  = (m0 + wm) >> 11;
        const int bh = (b << 4) + h;
        if (sel < 2) {
            #pragma unroll
            for (int it = 0; it < 8; ++it) {
                int row_l = it * 8 + rl;
                short8 vrow = *(const short8*)&Es[row_l * 72 + c8];
                int s = (m0 + wm + row_l) & 2047;
                *(short8*)(outQKV + (size_t)sel * 4194304 +
                           ((size_t)bh * S_ + s) * DH_ + c8) = vrow;
            }
        } else {
            const int s0 = (m0 + wm) & 2047;
            #pragma unroll
            for (int it = 0; it < 8; ++it) {
                int d_l = it * 8 + rl;
                short8 vrow = *(const short8*)&Es[d_l * 72 + c8];
                *(short8*)(outQKV + (size_t)2 * 4194304 +
                           ((size_t)bh << 17) + ((size_t)d_l << 11) + s0 + c8) = vrow;
            }
        }
    }
}

// ---------------------------------------------------------------------------
// Kernel 3: causal flash attention, 32-q waves, wave-group kv-split, DBUF.
// Block = (bh, q-tile j): 128 q-rows, 512 threads = 2 groups x 4 waves.
// Units of 64 kv; nu = 2(j+1); group A: units [0, j+1), B: [j+1, nu).
// Both groups run EXACTLY j+1 lockstep steps.  Wave wg owns q-rows
// q0 + wg*32 (same rows in both groups -> merged at end, R19 formula).
// Per group: K [64][64] via gl2lds src-swizzle; V^T [64 d][64 kv] reg-staged
// into permuted+swizzled LDS (R14 layout at width 64; b128 frag reads).
// Dbuf per group: 2 x (K 8KB + V 8KB) = 32KB; block total 64KB.
// Per step: prefetch unit+1 (K-DMA idle buf + V->8 VGPR) BEFORE compute,
// writeV after, ONE barrier.  Mask: wave-uniform dmask = kv0+63 > qr0.
// Grid 512: (j, 15-j) co-resident per CU -> uniform 17 steps/CU.
// ---------------------------------------------------------------------------
__global__ __launch_bounds__(512, 2) void attn_kernel(
    const short* __restrict__ Q, const short* __restrict__ Kh,
    const short* __restrict__ Vt, short* __restrict__ ctx)
{
    __shared__ __align__(16) short sm[32768];   // 64KB: grp g at g*16384, buf c at c*8192

    const int t    = threadIdx.x;
    const int lane = t & 63;
    const int w    = t >> 6;                     // 0..7
    const int wg   = w & 3;                      // wave within group
    const int g    = w >> 2;                     // 0 = A, 1 = B
    const int bid  = blockIdx.x;                 // 512 blocks

    const int lo  = bid & 255;
    const int xcd = lo & 7;
    const int idx = lo >> 3;                     // 0..31
    const int bh  = (xcd << 2) + (idx & 3);
    const int jb  = idx >> 2;                    // 0..7
    const int j   = (bid < 256) ? jb : (15 - jb);
    const int q0  = j * 128;
    const int ng  = j + 1;                       // 64-kv units per group
    const int pb  = g * ng;                      // group's first unit index
    const int qr0 = q0 + wg * 32;                // this wave's 32 q-rows

    const int lm = lane & 15;
    const int lg = lane >> 4;

    const short* Qb = Q  + (size_t)bh * S_ * DH_;
    const short* Kb = Kh + (size_t)bh * S_ * DH_;
    const short* Vb = Vt + ((size_t)bh << 17);

    // ---- staging helpers (R14/R17 layouts at kv-width 64, per-group) ----
    const int rsubK = lane >> 3;                         // 0..7
    const int cswK  = ((lane & 7) ^ rsubK) * 8;          // swizzled src chunk
    const int dV    = wg * 16 + (lane >> 2);             // V^T row this thread owns
    const int s3V   = dV & 7;

    // K unit [64 rows][64 shorts]: wave wg stages rows wg*16..+15 (2 DMAs)
    auto stageK = [&](int kv0, short* Kt) {
        #pragma unroll
        for (int i2 = 0; i2 < 2; ++i2) {
            const int rb = wg * 16 + i2 * 8;
            gl2lds16(Kb + (size_t)(kv0 + rb + rsubK) * 64 + cswK, Kt + rb * 64);
        }
    };
    // V unit: 16 d-rows/wave, 4 threads/row, 2 pieces of 8 shorts each
    auto loadV = [&](int kv0, short8* vld) {
        #pragma unroll
        for (int m = 0; m < 2; ++m) {
            const int cm = (lane & 3) + 4 * m;           // 8-short piece idx (0..7)
            vld[m] = *(const short8*)(Vb + (size_t)dV * 2048 + kv0 + cm * 8);
        }
    };
    auto writeV = [&](const short8* vld, short* Vp) {
        char* vrow = (char*)Vp + dV * 128;               // row = 64 shorts
        #pragma unroll
        for (int m = 0; m < 2; ++m) {
            const int cm = (lane & 3) + 4 * m;
            const int kk = (cm >> 2) & 1;
            const int q0off = ((cm & 1) << 4) + ((cm >> 1) & 1) * 4;  // shorts
            const int bA = (kk * 32 + q0off) * 2;                     // bytes
            const int pA = ((((bA >> 4) ^ s3V) << 4) | (bA & 15));
            const int bB = bA + 16;
            const int pB = ((((bB >> 4) ^ s3V) << 4) | (bB & 15));
            *(short4_t*)(vrow + pA) = __builtin_shufflevector(vld[m], vld[m], 0, 1, 2, 3);
            *(short4_t*)(vrow + pB) = __builtin_shufflevector(vld[m], vld[m], 4, 5, 6, 7);
        }
    };

    // Q as B-operand (pre-scaled by 0.125*log2e at the QKV GEMM):
    short8 qf[2][2];
    #pragma unroll
    for (int t2 = 0; t2 < 2; ++t2)
        #pragma unroll
        for (int kk = 0; kk < 2; ++kk)
            qf[t2][kk] = *(const short8*)(Qb + (size_t)(qr0 + t2 * 16 + lm) * DH_ + kk * 32 + lg * 8);

    float m_i[2] = {-1e30f, -1e30f}, l_i[2] = {0.f, 0.f};
    v4f o[2][4] = {};   // O^T[d = i*16+lg*4+r][q = t2*16+lm]

    // ---- prologue: stage first unit into buf0 ----
    short8 vpre[2];
    short* gB = sm + g * 16384;                  // group's 32KB region
    stageK(pb * 64, gB);
    loadV(pb * 64, vpre);
    writeV(vpre, gB + 4096);
    __syncthreads();            // drains K DMA (vmcnt) + V writes (lgkm)

    int cur = 0;
    for (int it = 0; it < ng; ++it) {
        const int kv0 = (pb + it) * 64;
        const bool pre = (it + 1 < ng);
        short* Kt = gB + cur * 8192;
        short* Vp = Kt + 4096;
        const bool dmask = (kv0 + 63) > qr0;     // wave-uniform

        // ---- prefetch next unit: K DMA into idle buffer, V into regs ----
        if (pre) {
            stageK(kv0 + 64, gB + (cur ^ 1) * 8192);
            loadV(kv0 + 64, vpre);
        }

        // ---- V^T A-frags from Vp: one swizzled 16B read each ----
        short8 vf[2][4];     // [kk][i]
        #pragma unroll
        for (int kk = 0; kk < 2; ++kk)
            #pragma unroll
            for (int i = 0; i < 4; ++i) {
                const int d = i * 16 + lm;
                const int ch = (kk * 4 + lg) ^ (lm & 7);
                vf[kk][i] = *(const short8*)((const char*)Vp + d * 128 + ch * 16);
            }

        // ---- S^T = K Q^T (16 MFMAs); kf from swizzled Kt ----
        short8 kf[2][4];
        #pragma unroll
        for (int kk = 0; kk < 2; ++kk)
            #pragma unroll
            for (int jj = 0; jj < 4; ++jj) {
                const int row = jj * 16 + lm;
                const int ch  = (kk * 4 + lg) ^ (lm & 7);
                kf[kk][jj] = *(const short8*)((const char*)Kt + row * 128 + ch * 16);
            }
        v4f sc[2][4] = {};   // [t2][jj]
        #pragma unroll
        for (int kk = 0; kk < 2; ++kk)
            #pragma unroll
            for (int t2 = 0; t2 < 2; ++t2)
                #pragma unroll
                for (int jj = 0; jj < 4; ++jj)
                    sc[t2][jj] = __builtin_amdgcn_mfma_f32_16x16x32_bf16(kf[kk][jj], qf[t2][kk], sc[t2][jj], 0, 0, 0);

        // one online-softmax step per t2 over 64 kv (R12-verified tile form)
        float alpha[2];
        short8 pf[2][2];     // [t2][kk]
        #pragma unroll
        for (int t2 = 0; t2 < 2; ++t2) {
            float x[4][4];
            const int q = qr0 + t2 * 16 + lm;
            #pragma unroll
            for (int jj = 0; jj < 4; ++jj)
                #pragma unroll
                for (int r = 0; r < 4; ++r) {
                    float v = sc[t2][jj][r];
                    if (dmask && (kv0 + jj * 16 + lg * 4 + r > q)) v = -1e30f;
                    x[jj][r] = v;
                }
            float m4[4];
            #pragma unroll
            for (int jj = 0; jj < 4; ++jj)
                m4[jj] = fmaxf(fmaxf(x[jj][0], x[jj][1]), fmaxf(x[jj][2], x[jj][3]));
            float rm = fmaxf(fmaxf(m4[0], m4[1]), fmaxf(m4[2], m4[3]));
            rm = fmaxf(rm, __shfl_xor(rm, 16, 64));
            rm = fmaxf(rm, __shfl_xor(rm, 32, 64));

            const float mn = fmaxf(m_i[t2], rm);
            alpha[t2] = EXP2(m_i[t2] - mn);
            m_i[t2] = mn;
            float s4[4];
            #pragma unroll
            for (int jj = 0; jj < 4; ++jj) {
                x[jj][0] = EXP2(x[jj][0] - mn); x[jj][1] = EXP2(x[jj][1] - mn);
                x[jj][2] = EXP2(x[jj][2] - mn); x[jj][3] = EXP2(x[jj][3] - mn);
                s4[jj] = (x[jj][0] + x[jj][1]) + (x[jj][2] + x[jj][3]);
            }
            float rs = (s4[0] + s4[1]) + (s4[2] + s4[3]);
            rs += __shfl_xor(rs, 16, 64);
            rs += __shfl_xor(rs, 32, 64);
            l_i[t2] = l_i[t2] * alpha[t2] + rs;

            #pragma unroll
            for (int kk = 0; kk < 2; ++kk) {
                union { short8 s; uint4 d; } pk;
                pk.d.x = pack2(x[2 * kk][0],     x[2 * kk][1]);
                pk.d.y = pack2(x[2 * kk][2],     x[2 * kk][3]);
                pk.d.z = pack2(x[2 * kk + 1][0], x[2 * kk + 1][1]);
                pk.d.w = pack2(x[2 * kk + 1][2], x[2 * kk + 1][3]);
                pf[t2][kk] = pk.s;
            }
        }

        #pragma unroll
        for (int t2 = 0; t2 < 2; ++t2)
            #pragma unroll
            for (int i = 0; i < 4; ++i)
                o[t2][i] *= alpha[t2];

        // O^T += V^T P^T  (16 MFMAs)
        #pragma unroll
        for (int kk = 0; kk < 2; ++kk)
            #pragma unroll
            for (int t2 = 0; t2 < 2; ++t2)
                #pragma unroll
                for (int i = 0; i < 4; ++i)
                    o[t2][i] = __builtin_amdgcn_mfma_f32_16x16x32_bf16(vf[kk][i], pf[t2][kk], o[t2][i], 0, 0, 0);

        // ---- write prefetched V into idle buffer, then ONE barrier ----
        if (pre) writeV(vpre, gB + (cur ^ 1) * 8192 + 4096);
        __syncthreads();   // drains K-DMA (vmcnt) + V ds_writes (lgkm);
                           // all waves' reads of buf[cur] complete
        cur ^= 1;
    }

    // ---- merge the two kv-halves: group B -> LDS, group A merges ----
    float* fb = (float*)sm;      // reuse K/V LDS: 4*64*36 floats = 36KB
    if (g == 1) {
        float* mp = &fb[(wg * 64 + lane) * 36];
        mp[0] = m_i[0]; mp[1] = l_i[0]; mp[2] = m_i[1]; mp[3] = l_i[1];
        #pragma unroll
        for (int t2 = 0; t2 < 2; ++t2)
            #pragma unroll
            for (int i = 0; i < 4; ++i)
                #pragma unroll
                for (int r = 0; r < 4; ++r)
                    mp[4 + t2 * 16 + i * 4 + r] = o[t2][i][r];
    }
    __syncthreads();
    if (g == 0) {
        const float* mp = &fb[(wg * 64 + lane) * 36];
        #pragma unroll
        for (int t2 = 0; t2 < 2; ++t2) {
            const float mo = mp[t2 * 2];
            const float lo = mp[t2 * 2 + 1];
            const float mn = fmaxf(m_i[t2], mo);
            const float sa = EXP2(m_i[t2] - mn);
            const float sb = EXP2(mo - mn);
            l_i[t2] = l_i[t2] * sa + lo * sb;
            #pragma unroll
            for (int i = 0; i < 4; ++i)
                #pragma unroll
                for (int r = 0; r < 4; ++r)
                    o[t2][i][r] = o[t2][i][r] * sa + mp[4 + t2 * 16 + i * 4 + r] * sb;
        }

        // epilogue: ctx[b*S + q][hd*64 + d] = O/l, 8B stores
        const int b = bh >> 4, hd = bh & 15;
        #pragma unroll
        for (int t2 = 0; t2 < 2; ++t2) {
            const float inv = 1.f / l_i[t2];
            const size_t base = ((size_t)(b * S_ + qr0 + t2 * 16 + lm) << 10) + (hd << 6) + lg * 4;
            #pragma unroll
            for (int i = 0; i < 4; ++i) {
                short4_t s4;
                #pragma unroll
                for (int r = 0; r < 4; ++r) s4[r] = f2bf(o[t2][i][r] * inv);
                *(short4_t*)(ctx + base + i * 16) = s4;
            }
        }
    }
}

// ---------------------------------------------------------------------------
extern "C" void kernel_launch(void* const* d_in, const int* in_sizes, int n_in,
                              void* d_out, int out_size, void* d_ws, size_t ws_size,
                              hipStream_t stream) {
    const float* X  = (const float*)d_in[0];
    const float* Wq = (const float*)d_in[2];
    const float* bq = (const float*)d_in[3];
    const float* Wk = (const float*)d_in[4];
    const float* bk = (const float*)d_in[5];
    const float* Wv = (const float*)d_in[6];
    const float* bv = (const float*)d_in[7];
    const float* Wo = (const float*)d_in[8];
    const float* bo = (const float*)d_in[9];
    float* out = (float*)d_out;

    short* ws  = (short*)d_ws;
    short* Xb  = ws;                          // X bf16, 4,194,304
    short* Wb  = Xb + 4194304;                // [Wq|Wk|Wv|Wo] bf16
    short* Qh  = Wb + 4194304;                // [bh][s][64]  (pre-scaled)
    short* Kb  = Qh + 4194304;                // [bh][s][64]
    short* Vt  = Kb + 4194304;                // [bh][64][s] (written by gemm)
    short* Ctx = Vt + 4194304;                // [b*s][1024]

    cast_kernel<<<4096, 256, 0, stream>>>(X, Wq, Wk, Wv, Wo, Xb, Wb);

    // fused QKV projection: flat grid 24*32 = 768, swizzled in-kernel
    gemm_kernel<128, 0><<<768, 256, 0, stream>>>(
        Xb, Wb, bq, bk, bv, Qh, M_, 3 * D_, D_);

    // 32q-wave kv-split dbuf attention: 512 blocks x 512 threads
    attn_kernel<<<512, 512, 0, stream>>>(Qh, Kb, Vt, Ctx);

    // output projection: flat grid 16*32 = 512, swizzled in-kernel (2/CU)
    gemm_kernel<64, 2><<<512, 256, 0, stream>>>(
        Ctx, Wb + 3145728, bo, bo, bo, out, M_, D_, D_);
}